// Round 15
// baseline (379.506 us; speedup 1.0000x reference)
//
#include <hip/hip_runtime.h>

// WaveFDTD2D, persistent fenceless-sync kernel, BOUNDARY-ONLY LDS (r27).
// Ledger: r16/r20b/r26 = 260-264us; barrier count, protocol trims, ILP
// shape, sync mechanism, poll subsets all neutral; >1 block/CU impossible
// (coop rejects silently / regular hangs). Remaining un-falsified wall term:
// the per-CU LDS pipe, serialized across 16 waves (~6 DS instrs/wave/substep
// ~= 500-700cy of the ~1200cy substep wall).
// r27 cuts LDS traffic ~3x: only BOUNDARY rows cross waves. Wave w's halo
// reads are rows 4w-1 = 4(w-1)+3 and 4w+4 = 4(w+1) -- always a neighbor's
// first/last row. Rows 4w+1, 4w+2 never leave registers. LDS = 2 boundary
// rows/wave (34 slots w/ dummies, 17.4KB): per substep per wave 1 fused
// write-pair + 1 fused read2st64 instead of ~6 DS ops. Receiver LDS read
// removed via r22's VALIDATED register capture (owner thread stores post-
// injection rCur straight to out; r22's regression was its flag polls, not
// this). Source updates the LDS copy only when its row is boundary (i=0/3).
// Slot map: row 4w -> 2w+1, row 4w+3 -> 2w+2; dummies 0 (="row -1") and
// 33 (="row 64") zero forever. Wave w reads slots 2w, 2w+3 (offsets {0,3}
// st64 units, wave-uniform base + lane ez -> ds_read2st64_b32, stride-1 b32,
// conflict-free). All else byte-identical to r20b (passing): block-local
// init, agent-scope coherent-point exchange, full 8-neighbor all-wave poll,
// no prefill (s=0 x-halo from global, guard rows), exact L1 cone skip,
// one-shot prefix publish, V2-in-registers.

#define NXd 512
#define NZd 512
#define NSTEPSd 512
#define NRECd 128
#define DT2f 1.0e-6f
#define INVf 1.0e-2f
#define TBk 16
#define TIk 32
#define EXTk 64
#define NTILEk 16
#define PADk 16
#define PWk 544              // NXd + 2*PADk = 16*34
#define LSLOTS 34            // 1 dummy + 32 boundary rows + 1 dummy
#define NROUNDS (NSTEPSd / TBk)
#define MAXR 8               // max receivers owned by one thread

__device__ __forceinline__ float dpp_shr1(float x) {  // lane i <- lane i-1
    int v = __builtin_amdgcn_update_dpp(0, __builtin_bit_cast(int, x),
                                        0x138, 0xF, 0xF, false);  // WAVE_SHR:1
    return __builtin_bit_cast(float, v);
}
__device__ __forceinline__ float dpp_shl1(float x) {  // lane i <- lane i+1
    int v = __builtin_amdgcn_update_dpp(0, __builtin_bit_cast(int, x),
                                        0x130, 0xF, 0xF, false);  // WAVE_SHL:1
    return __builtin_bit_cast(float, v);
}

// Coherent-point (agent-scope) field accesses: bypass L1/L2, hit L3.
__device__ __forceinline__ float2 ldg_f2(const float2* p) {
    unsigned long long v = __hip_atomic_load(
        (const unsigned long long*)p, __ATOMIC_RELAXED, __HIP_MEMORY_SCOPE_AGENT);
    return __builtin_bit_cast(float2, v);
}
__device__ __forceinline__ float ldg_f1(const float* p) {
    unsigned v = __hip_atomic_load(
        (const unsigned*)p, __ATOMIC_RELAXED, __HIP_MEMORY_SCOPE_AGENT);
    return __builtin_bit_cast(float, v);
}
__device__ __forceinline__ void stg_f2(float2* p, float2 x) {
    __hip_atomic_store((unsigned long long*)p,
                       __builtin_bit_cast(unsigned long long, x),
                       __ATOMIC_RELAXED, __HIP_MEMORY_SCOPE_AGENT);
}

__global__ __launch_bounds__(1024) void fdtd_persist(
    const float* __restrict__ vel, const float* __restrict__ source,
    const int* __restrict__ src_x, const int* __restrict__ src_z,
    const int* __restrict__ rec_x, const int* __restrict__ rec_z,
    float2* __restrict__ PA, float2* __restrict__ PB,
    float* __restrict__ out, unsigned* __restrict__ done)
{
    __shared__ float sb[2][LSLOTS * EXTk];   // boundary rows only, 17.4KB

    const int tid = threadIdx.x;
    const int w   = tid >> 6;       // 16 waves, wave w owns ext rows 4w..4w+3
    const int ez  = tid & 63;       // lane -> ext z coord
    const int bx = blockIdx.x, by = blockIdx.y;
    const int gx0 = by * TIk;
    const int gz0 = bx * TIk;
    const int ox = gx0 - TBk, oz = gz0 - TBk;
    const int myid = (by * NTILEk + bx) * 32;   // 128B-strided counter slot

    // ---- Block-local init: zero own 34x34 padded patch of PA and PB ----
    for (int i = tid; i < 34 * 34; i += 1024) {
        const int p = (by * 34 + i / 34) * PWk + (bx * 34 + i % 34);
        stg_f2(&PA[p], make_float2(0.f, 0.f));
        stg_f2(&PB[p], make_float2(0.f, 0.f));
    }

    // ---- Receiver ownership by COMPUTING thread (r22-validated capture) ----
    // Thread (w, ez) owns cells (ext rows 4w..4w+3, col ez); receivers are
    // interior (rows/cols 16..47) -> waves 4..11. Static-indexed arrays.
    int nR = 0; int rSlot[MAXR]; int rReg[MAXR];
    for (int r = 0; r < NRECd; ++r) {
        const int er = rec_x[r] - ox, ec = rec_z[r] - oz;
        if (er >= TBk && er < TBk + TIk && ec >= TBk && ec < TBk + TIk &&
            ec == ez && (er >> 2) == w && nR < MAXR) {
            rSlot[nR] = r; rReg[nR] = er & 3; ++nR;
        }
    }
    // Zero owned receivers' out rows (harness poisons; skipped rounds = 0).
    for (int j = 0; j < nR; ++j) {
        float4* o4 = (float4*)&out[rSlot[j] * NSTEPSd];
        for (int q = 0; q < NSTEPSd / 4; ++q) o4[q] = make_float4(0.f, 0.f, 0.f, 0.f);
    }

    // V2 in 4 registers per thread: v^2*dt^2/(dx*dz), 0 in the apron.
    float rV2i[4];
    {
        const int fz = oz + ez;
        #pragma unroll
        for (int i = 0; i < 4; ++i) {
            const int fx = ox + 4 * w + i;
            float v2 = 0.f;
            if (fx >= 0 && fx < NXd && fz >= 0 && fz < NZd) {
                float v = vel[fx * NZd + fz];
                v2 = v * v * (DT2f * INVf);
            }
            rV2i[i] = v2;
        }
    }

    // Dummy slots 0 ("row -1") and 33 ("row 64"), both buffers, zero forever.
    if (w == 0) {
        sb[0][ez] = 0.f;
        sb[0][(LSLOTS - 1) * EXTk + ez] = 0.f;
        sb[1][ez] = 0.f;
        sb[1][(LSLOTS - 1) * EXTk + ez] = 0.f;
    }

    // Source ownership (owner = lane ezs of wave exs>>2, register exs&3).
    const int sx = *src_x, sz = *src_z;
    const int exs = sx - ox, ezs = sz - oz;
    const bool srcHere = (exs >= 0 && exs < EXTk && ezs >= 0 && ezs < EXTk) &&
                         (tid == (((exs >> 2) << 6) | ezs));

    // Exact L1 cone: active at round k iff dman <= 16k+17.
    const int dxm = max(0, max(ox - sx, sx - (ox + EXTk - 1)));
    const int dzm = max(0, max(oz - sz, sz - (oz + EXTk - 1)));
    const int dman = dxm + dzm;
    const int kAct = dman <= (TBk + 1) ? 0 : (dman - (TBk + 1) + TBk - 1) / TBk;

    // All-wave polling: lanes 0-7 of each wave watch the 8 neighbors
    // (clamped; clamp->self benign: own counter == k+1 entering round k).
    const int lane = tid & 63;
    int nb = myid;
    if (lane < 8) {
        const int d = (lane < 4) ? lane : lane + 1;       // skip center
        const int ny = min(NTILEk - 1, max(0, by + d / 3 - 1));
        const int nx = min(NTILEk - 1, max(0, bx + d % 3 - 1));
        nb = (ny * NTILEk + nx) * 32;
    }

    const int pbase = (gx0 + 4 * w) * PWk + gz0 + ez;  // padded global index
    const int hbase = (2 * w) * EXTk + ez;   // halo read base: slot 2w
    const int wb0   = (2 * w + 1) * EXTk + ez;   // write slot for row 4w
    const int wb3   = (2 * w + 2) * EXTk + ez;   // write slot for row 4w+3

    // Publish init + entire cone-skipped prefix in one release store
    // (barrier drains every wave's vmcnt; agent stores visible at L3).
    __syncthreads();
    if (tid == 0)
        __hip_atomic_store(&done[myid], (unsigned)(kAct + 1),
                           __ATOMIC_RELAXED, __HIP_MEMORY_SCOPE_AGENT);

    // ---- Rounds kAct..31; monotone cone => always active once started ----
    for (int k = kAct; k < NROUNDS; ++k) {
        const int t0 = TBk * k;

        // Per-wave wait: 8 neighbors finished round k-1 (reads AND writes).
        if (lane < 8) {
            const unsigned tgt = (unsigned)(k + 1);
            for (;;) {
                unsigned seen = __hip_atomic_load(&done[nb], __ATOMIC_RELAXED,
                                                  __HIP_MEMORY_SCOPE_AGENT);
                if (seen >= tgt) break;
                if (seen + 1 < tgt) __builtin_amdgcn_s_sleep(16);
                else                __builtin_amdgcn_s_sleep(1);
            }
        }

        float2* __restrict__ Pin  = (k & 1) ? PB : PA;
        float2* __restrict__ Pout = (k & 1) ? PA : PB;

        // Unconditional padded agent loads (apron zeros / tolerated rim).
        float2 co[4];
        #pragma unroll
        for (int i = 0; i < 4; ++i) co[i] = ldg_f2(&Pin[pbase + i * PWk]);
        // Substep-0 x-halo direct from global: cur of ext rows 4w-1, 4w+4.
        const float huG = ldg_f1((const float*)&Pin[pbase - PWk]);
        const float hdG = ldg_f1((const float*)&Pin[pbase + 4 * PWk]);

        float rCur[4], rOld[4];
        #pragma unroll
        for (int i = 0; i < 4; ++i) { rCur[i] = co[i].x; rOld[i] = co[i].y; }

        float sv[TBk];
        if (srcHere) {
            #pragma unroll
            for (int s = 0; s < TBk; ++s) sv[s] = source[t0 + s] * DT2f;
        }

        // ---- 16 sub-steps, fully unrolled; s=0 uses global halo ----
        #pragma unroll
        for (int s = 0; s < TBk; ++s) {
            const float* cur = sb[s & 1];
            float* nxt = sb[(s & 1) ^ 1];
            // x-halo: s=0 from global regs; s>=1 one ds_read2st64_b32
            // (slots 2w, 2w+3 = neighbor boundary rows 4w-1, 4w+4;
            //  edge waves hit the zero dummies).
            const float up0 = (s == 0) ? huG : cur[hbase];
            const float dn3 = (s == 0) ? hdG : cur[hbase + 3 * EXTk];
            float nv[4];
            #pragma unroll
            for (int i = 0; i < 4; ++i) {
                const float up = (i == 0) ? up0 : rCur[i - 1];
                const float dn = (i == 3) ? dn3 : rCur[i + 1];
                const float lf = dpp_shr1(rCur[i]);     // z-1 neighbor
                const float rt = dpp_shl1(rCur[i]);     // z+1 neighbor
                const float sum = (up + dn) + (lf + rt);
                const float t4 = __builtin_fmaf(-4.0f, rCur[i], sum);
                const float pm = __builtin_fmaf(2.0f, rCur[i], -rOld[i]);
                nv[i] = __builtin_fmaf(rV2i[i], t4, pm);
            }
            #pragma unroll
            for (int i = 0; i < 4; ++i) { rOld[i] = rCur[i]; rCur[i] = nv[i]; }
            // BOUNDARY-ONLY LDS commit: rows 4w and 4w+3 (fusable write pair).
            nxt[wb0] = nv[0];
            nxt[wb3] = nv[3];
            // Source injection (post-stencil, pre-recording); LDS copy
            // refreshed only if the source row is a boundary row.
            if (srcHere) {
                #pragma unroll
                for (int i = 0; i < 4; ++i) {
                    if (i == (exs & 3)) {
                        rCur[i] += sv[s];
                        if (i == 0) nxt[wb0] = rCur[0];
                        if (i == 3) nxt[wb3] = rCur[3];
                    }
                }
            }
            // Receiver capture from registers (post-injection), straight to
            // global (r22-validated). Non-owner threads: one cheap branch.
            if (nR) {
                #pragma unroll
                for (int j = 0; j < MAXR; ++j) {
                    if (j < nR) {
                        const int rr = rReg[j];
                        const float v = rr == 0 ? rCur[0] : rr == 1 ? rCur[1]
                                      : rr == 2 ? rCur[2] : rCur[3];
                        out[rSlot[j] * NSTEPSd + t0 + s] = v;
                    }
                }
            }
            __syncthreads();
        }

        // Store interior (ext rows 16..47 = waves 4..11, ez 16..47): agent
        // stores, visible to neighbors' agent loads without any fence.
        if (w >= 4 && w < 12 && ez >= TBk && ez < EXTk - TBk) {
            #pragma unroll
            for (int i = 0; i < 4; ++i)
                stg_f2(&Pout[pbase + i * PWk], make_float2(rCur[i], rOld[i]));
        }

        // Pre-publish barrier: every wave's vmcnt (agent-store acks) drained
        // before tid 0 issues the counter store; also serializes LDS rounds.
        __syncthreads();
        if (tid == 0)
            __hip_atomic_store(&done[myid], (unsigned)(k + 2),
                               __ATOMIC_RELAXED, __HIP_MEMORY_SCOPE_AGENT);
    }
}

extern "C" void kernel_launch(void* const* d_in, const int* in_sizes, int n_in,
                              void* d_out, int out_size, void* d_ws, size_t ws_size,
                              hipStream_t stream) {
    const float* vel    = (const float*)d_in[0];
    const float* source = (const float*)d_in[1];
    const int*   src_x  = (const int*)d_in[2];
    const int*   src_z  = (const int*)d_in[3];
    const int*   rec_x  = (const int*)d_in[4];
    const int*   rec_z  = (const int*)d_in[5];
    float* out = (float*)d_out;

    const size_t FP = (size_t)PWk * PWk;
    // Guard rows: [guard PWk][PA FP][PB FP][guard PWk][DONE].
    float2* base = (float2*)d_ws;
    float2* PA = base + PWk;
    float2* PB = PA + FP;
    unsigned* DONE = (unsigned*)(PB + FP + PWk);   // 256 counters, 128B stride

    hipMemsetAsync(DONE, 0, (size_t)NTILEk * NTILEk * 32 * sizeof(unsigned), stream);

    void* args[] = {(void*)&vel, (void*)&source, (void*)&src_x, (void*)&src_z,
                    (void*)&rec_x, (void*)&rec_z, (void*)&PA, (void*)&PB,
                    (void*)&out, (void*)&DONE};
    hipLaunchCooperativeKernel((void*)fdtd_persist, dim3(NTILEk, NTILEk),
                               dim3(1024), args, 0, stream);
}

// Round 16
// 342.478 us; speedup vs baseline: 1.1081x; 1.1081x over previous
//
#include <hip/hip_runtime.h>

// WaveFDTD2D FINAL (r28 = r20b revert): persistent fenceless-sync kernel.
// Best validated: 261.9us dispatch / 338.4us bench (vs 360.6us session start).
// DECLARED STRUCTURAL FLOOR for this algorithm/platform: 512 sequential
// substeps x (barrier reconvergence ~240cy + LDS halo latency ~120cy +
// stencil issue ~260cy) at the platform-max 1 block/CU >= ~215us; measured
// 260us incl. 32 round handshakes (~2us: poll + L3 halo load + publish).
// Falsified levers (r14-r27): grid.sync (30us/round); threadfence sync
// (13us/round); barrier count (trapezoid S=2 AoS/SoA: VALU premium wins);
// protocol trims (neutral); per-wave ILP 8x8 (worse); elastic per-wave flag
// sync (worse); dependency-subset polls (neutral); boundary-only LDS
// (worse); >1 block/CU (cooperative launcher REJECTS 512-block grids
// silently -> all-zero output; regular launch HANGS on non-resident
// neighbors). Working structure:
//  - one cooperative launch, 256 blocks (1/CU), 16 waves x 4 rows, tile
//    32x32, ext 64x64 (T=16 temporal block, redundancy-optimal).
//  - cross-block exchange via RELAXED AGENT-SCOPE loads/stores (bypass
//    non-coherent L1/L2, served by die-level Infinity Cache) -> NO fences.
//  - fenceless 8-neighbor counter sync; all-wave polling; exact L1 cone
//    skip with one-shot prefix publish.
//  - no prefill: s=0 x-halo direct from global (guard rows in workspace);
//    LDS ping-pong + DPP z-neighbors; V2 in registers; receiver rv[]
//    buffering with post-publish flush.

#define NXd 512
#define NZd 512
#define NSTEPSd 512
#define NRECd 128
#define DT2f 1.0e-6f
#define INVf 1.0e-2f
#define TBk 16
#define TIk 32
#define EXTk 64
#define NTILEk 16
#define PADk 16
#define PWk 544              // NXd + 2*PADk = 16*34
#define LROWS 66             // 1 dummy + 64 ext rows + 1 dummy
#define NROUNDS (NSTEPSd / TBk)

__device__ __forceinline__ float dpp_shr1(float x) {  // lane i <- lane i-1
    int v = __builtin_amdgcn_update_dpp(0, __builtin_bit_cast(int, x),
                                        0x138, 0xF, 0xF, false);  // WAVE_SHR:1
    return __builtin_bit_cast(float, v);
}
__device__ __forceinline__ float dpp_shl1(float x) {  // lane i <- lane i+1
    int v = __builtin_amdgcn_update_dpp(0, __builtin_bit_cast(int, x),
                                        0x130, 0xF, 0xF, false);  // WAVE_SHL:1
    return __builtin_bit_cast(float, v);
}

// Coherent-point (agent-scope) field accesses: bypass L1/L2, hit L3.
__device__ __forceinline__ float2 ldg_f2(const float2* p) {
    unsigned long long v = __hip_atomic_load(
        (const unsigned long long*)p, __ATOMIC_RELAXED, __HIP_MEMORY_SCOPE_AGENT);
    return __builtin_bit_cast(float2, v);
}
__device__ __forceinline__ float ldg_f1(const float* p) {
    unsigned v = __hip_atomic_load(
        (const unsigned*)p, __ATOMIC_RELAXED, __HIP_MEMORY_SCOPE_AGENT);
    return __builtin_bit_cast(float, v);
}
__device__ __forceinline__ void stg_f2(float2* p, float2 x) {
    __hip_atomic_store((unsigned long long*)p,
                       __builtin_bit_cast(unsigned long long, x),
                       __ATOMIC_RELAXED, __HIP_MEMORY_SCOPE_AGENT);
}

__global__ __launch_bounds__(1024) void fdtd_persist(
    const float* __restrict__ vel, const float* __restrict__ source,
    const int* __restrict__ src_x, const int* __restrict__ src_z,
    const int* __restrict__ rec_x, const int* __restrict__ rec_z,
    float2* __restrict__ PA, float2* __restrict__ PB,
    float* __restrict__ out, unsigned* __restrict__ done)
{
    __shared__ float sb[2][LROWS * EXTk];

    const int tid = threadIdx.x;
    const int w   = tid >> 6;       // 16 waves, wave w owns ext rows 4w..4w+3
    const int ez  = tid & 63;       // lane -> ext z coord
    const int bx = blockIdx.x, by = blockIdx.y;
    const int gx0 = by * TIk;
    const int gz0 = bx * TIk;
    const int ox = gx0 - TBk, oz = gz0 - TBk;
    const int myid = (by * NTILEk + bx) * 32;   // 128B-strided counter slot

    // ---- Block-local init: zero own 34x34 padded patch of PA and PB ----
    for (int i = tid; i < 34 * 34; i += 1024) {
        const int p = (by * 34 + i / 34) * PWk + (bx * 34 + i % 34);
        stg_f2(&PA[p], make_float2(0.f, 0.f));
        stg_f2(&PB[p], make_float2(0.f, 0.f));
    }

    // O(1) receiver ownership; owning block zeros its receivers' out rows.
    bool rOwn = false; int rIdx = 0;
    if (tid < NRECd) {
        const int rx = rec_x[tid], rz = rec_z[tid];
        rOwn = (rx >= gx0 && rx < gx0 + TIk && rz >= gz0 && rz < gz0 + TIk);
        rIdx = (rx - ox + 1) * EXTk + (rz - oz);    // buffer row = ext row + 1
        if (rOwn) {
            float4* o4 = (float4*)&out[tid * NSTEPSd];
            #pragma unroll
            for (int j = 0; j < NSTEPSd / 4; ++j) o4[j] = make_float4(0.f, 0.f, 0.f, 0.f);
        }
    }

    // V2 in 4 registers per thread for the whole run: v^2*dt^2/(dx*dz),
    // 0 in the apron (zero BC) -- never touches global memory.
    float rV2i[4];
    {
        const int fz = oz + ez;
        #pragma unroll
        for (int i = 0; i < 4; ++i) {
            const int fx = ox + 4 * w + i;
            float v2 = 0.f;
            if (fx >= 0 && fx < NXd && fz >= 0 && fz < NZd) {
                float v = vel[fx * NZd + fz];
                v2 = v * v * (DT2f * INVf);
            }
            rV2i[i] = v2;
        }
    }

    // Dummy LDS rows (0 and 65) zero in BOTH buffers; never rewritten.
    if (w == 0) {
        sb[0][ez] = 0.f;
        sb[0][(LROWS - 1) * EXTk + ez] = 0.f;
        sb[1][ez] = 0.f;
        sb[1][(LROWS - 1) * EXTk + ez] = 0.f;
    }

    // Source ownership (owner = lane ezs of wave exs>>2, register exs&3).
    const int sx = *src_x, sz = *src_z;
    const int exs = sx - ox, ezs = sz - oz;
    const bool srcHere = (exs >= 0 && exs < EXTk && ezs >= 0 && ezs < EXTk) &&
                         (tid == (((exs >> 2) << 6) | ezs));

    // Exact L1 cone: active at round k iff dman <= 16k+17.
    const int dxm = max(0, max(ox - sx, sx - (ox + EXTk - 1)));
    const int dzm = max(0, max(oz - sz, sz - (oz + EXTk - 1)));
    const int dman = dxm + dzm;
    const int kAct = dman <= (TBk + 1) ? 0 : (dman - (TBk + 1) + TBk - 1) / TBk;

    // Every wave polls: lanes 0-7 of each wave watch the 8 neighbors
    // (clamped; clamp->self benign: own counter == k+1 entering round k).
    const int lane = tid & 63;
    int nb = myid;
    if (lane < 8) {
        const int d = (lane < 4) ? lane : lane + 1;       // skip center
        const int ny = min(NTILEk - 1, max(0, by + d / 3 - 1));
        const int nx = min(NTILEk - 1, max(0, bx + d % 3 - 1));
        nb = (ny * NTILEk + nx) * 32;
    }

    const int pbase = (gx0 + 4 * w) * PWk + gz0 + ez;  // padded global index
    const int fbase = 4 * w * EXTk + ez;   // buffer row 4w (ext row 4w-1)

    // Publish init + entire cone-skipped prefix in one release store
    // (barrier drains every wave's vmcnt; agent stores visible at L3).
    __syncthreads();
    if (tid == 0)
        __hip_atomic_store(&done[myid], (unsigned)(kAct + 1),
                           __ATOMIC_RELAXED, __HIP_MEMORY_SCOPE_AGENT);

    // ---- Rounds kAct..31; monotone cone => always active once started ----
    for (int k = kAct; k < NROUNDS; ++k) {
        const int t0 = TBk * k;

        // Per-wave wait: 8 neighbors finished round k-1 (reads AND writes).
        // No barrier after: each wave independently gates its own loads;
        // LDS hazards are covered by the pre-publish barrier of round k-1.
        if (lane < 8) {
            const unsigned tgt = (unsigned)(k + 1);
            for (;;) {
                unsigned seen = __hip_atomic_load(&done[nb], __ATOMIC_RELAXED,
                                                  __HIP_MEMORY_SCOPE_AGENT);
                if (seen >= tgt) break;
                if (seen + 1 < tgt) __builtin_amdgcn_s_sleep(16);
                else                __builtin_amdgcn_s_sleep(1);
            }
        }

        float2* __restrict__ Pin  = (k & 1) ? PB : PA;
        float2* __restrict__ Pout = (k & 1) ? PA : PB;

        // Unconditional padded agent loads (apron zeros / tolerated rim).
        float2 co[4];
        #pragma unroll
        for (int i = 0; i < 4; ++i) co[i] = ldg_f2(&Pin[pbase + i * PWk]);
        // Substep-0 x-halo direct from global: cur of ext rows 4w-1, 4w+4.
        // Edge blocks read guard rows (allocated; values tolerated).
        const float huG = ldg_f1((const float*)&Pin[pbase - PWk]);
        const float hdG = ldg_f1((const float*)&Pin[pbase + 4 * PWk]);

        float rCur[4], rOld[4];
        #pragma unroll
        for (int i = 0; i < 4; ++i) { rCur[i] = co[i].x; rOld[i] = co[i].y; }

        float sv[TBk];
        if (srcHere) {
            #pragma unroll
            for (int s = 0; s < TBk; ++s) sv[s] = source[t0 + s] * DT2f;
        }

        // ---- 16 sub-steps, fully unrolled; s=0 uses global halo ----
        float rv[TBk];
        #pragma unroll
        for (int s = 0; s < TBk; ++s) {
            const float* cur = sb[s & 1];
            float* nxt = sb[(s & 1) ^ 1];
            // x-halo: s=0 from global regs; s>=1 wave-uniform ds_read2st64
            // (ext rows 4w-1, 4w+4; edge waves hit zero dummies).
            const float up0 = (s == 0) ? huG : cur[fbase];
            const float dn3 = (s == 0) ? hdG : cur[fbase + 5 * EXTk];
            float nv[4];
            #pragma unroll
            for (int i = 0; i < 4; ++i) {
                const float up = (i == 0) ? up0 : rCur[i - 1];
                const float dn = (i == 3) ? dn3 : rCur[i + 1];
                const float lf = dpp_shr1(rCur[i]);     // z-1 neighbor
                const float rt = dpp_shl1(rCur[i]);     // z+1 neighbor
                const float sum = (up + dn) + (lf + rt);
                const float t4 = __builtin_fmaf(-4.0f, rCur[i], sum);
                const float pm = __builtin_fmaf(2.0f, rCur[i], -rOld[i]);
                nv[i] = __builtin_fmaf(rV2i[i], t4, pm);
            }
            #pragma unroll
            for (int i = 0; i < 4; ++i) {
                rOld[i] = rCur[i];
                rCur[i] = nv[i];
                nxt[fbase + (1 + i) * EXTk] = nv[i];    // buffer row 4w+1+i
            }
            // Source injection (post-stencil, pre-recording).
            if (srcHere) {
                #pragma unroll
                for (int i = 0; i < 4; ++i) {
                    if (i == (exs & 3)) {
                        rCur[i] += sv[s];
                        nxt[(exs + 1) * EXTk + ezs] = rCur[i];
                    }
                }
            }
            __syncthreads();
            // Receiver sample of field@t0+s (post-injection). Next substep
            // writes the OTHER buffer -> race-free with one barrier.
            if (rOwn) rv[s] = nxt[rIdx];
        }

        // Store interior (ext rows 16..47 = waves 4..11, ez 16..47): agent
        // stores, visible to neighbors' agent loads without any fence.
        if (w >= 4 && w < 12 && ez >= TBk && ez < EXTk - TBk) {
            #pragma unroll
            for (int i = 0; i < 4; ++i)
                stg_f2(&Pout[pbase + i * PWk], make_float2(rCur[i], rOld[i]));
        }

        // Pre-publish barrier: every wave's vmcnt (agent-store acks) drained
        // before tid 0 issues the counter store. Also the block-internal
        // round serializer for the all-wave-poll scheme.
        __syncthreads();
        if (tid == 0)
            __hip_atomic_store(&done[myid], (unsigned)(k + 2),
                               __ATOMIC_RELAXED, __HIP_MEMORY_SCOPE_AGENT);

        // Receiver flush AFTER publish (block-private, off critical path).
        if (rOwn) {
            #pragma unroll
            for (int s = 0; s < TBk; ++s)
                out[tid * NSTEPSd + t0 + s] = rv[s];
        }
    }
}

extern "C" void kernel_launch(void* const* d_in, const int* in_sizes, int n_in,
                              void* d_out, int out_size, void* d_ws, size_t ws_size,
                              hipStream_t stream) {
    const float* vel    = (const float*)d_in[0];
    const float* source = (const float*)d_in[1];
    const int*   src_x  = (const int*)d_in[2];
    const int*   src_z  = (const int*)d_in[3];
    const int*   rec_x  = (const int*)d_in[4];
    const int*   rec_z  = (const int*)d_in[5];
    float* out = (float*)d_out;

    const size_t FP = (size_t)PWk * PWk;
    // Guard rows: [guard PWk][PA FP][PB FP][guard PWk][DONE]. PA's top OOB
    // (row -1) lands in the leading guard; PB's bottom OOB (row PWk) lands
    // in the trailing guard; PA-bottom/PB-top OOB land inside PB/PA.
    float2* base = (float2*)d_ws;
    float2* PA = base + PWk;
    float2* PB = PA + FP;
    unsigned* DONE = (unsigned*)(PB + FP + PWk);   // 256 counters, 128B stride

    hipMemsetAsync(DONE, 0, (size_t)NTILEk * NTILEk * 32 * sizeof(unsigned), stream);

    void* args[] = {(void*)&vel, (void*)&source, (void*)&src_x, (void*)&src_z,
                    (void*)&rec_x, (void*)&rec_z, (void*)&PA, (void*)&PB,
                    (void*)&out, (void*)&DONE};
    hipLaunchCooperativeKernel((void*)fdtd_persist, dim3(NTILEk, NTILEk),
                               dim3(1024), args, 0, stream);
}